// Round 21
// baseline (1468.915 us; speedup 1.0000x reference)
//
#include <hip/hip_runtime.h>
#include <math.h>

// ---------------------------------------------------------------------------
// Dictionary_56212531970303 : FISTA dictionary forward on MI355X, fp32.
// Layout: coefficient state [b][ch][pix]. Per-INSTRUCTION contiguity rule
// (round-13): state loads/stores = 64 lanes x (float4|float2) contiguous.
// Round-19: c-buffer pointer rotation (3-buffer cycle; !act writes fix-up).
// Round-20: kB1 rolling-row accumulation — thread = 1ch x 4 out-rows x 8px,
// 12-row input window loaded ONCE (18x -> 6x amplification, 302->100MB L2);
// 16-ch shfl_xor reduce; coefs via padded atomsP float4 rows. NPG 32->4.
// Setup: prep1, k_PP, k_impulse, k_dft, atoms1, k_M, k_M2 x4, k_fin.
// NOTE: every "if (tid<N)" with N>blockDim must be a grid-stride loop —
// round-2/3 regression (absmax 0.134).
// ---------------------------------------------------------------------------

#define NB 4
#define NCH 64
#define NPIX 16384              // 128*128
#define NPB (NCH*NPIX)
#define NCOEF (NB*NCH*NPIX)     // 4194304
#define NIMG  (NB*NPIX)         // 65536
#define NPG 4                   // partial channel-groups (16 ch each)
#define TOLV 1e-4f

#define SC_BETA 0
#define SC_L    1
#define SC_G    4
#define SC_G2   5
#define SC_LPK2 6

// ---------------------------------------------------------------------------
// prep1: one block. bjorck via 8x8 gram-iteration; writes gram + pf + scalars.
__global__ __launch_bounds__(256) void k_prep1(const float* __restrict__ fatoms,
    const float* __restrict__ beta_p,
    float* __restrict__ gram_g, float* __restrict__ pf_g,
    float* __restrict__ scalars)
{
    __shared__ float sW[648], sWf[648];
    __shared__ float sG[64], sP[64], sF[64], sT[64], sTmp[64];
    __shared__ float sGr[6561];
    __shared__ float rs[81];
    __shared__ float sSig;
    int tid = threadIdx.x;
    if (tid==0){ float b=beta_p[0]; scalars[SC_BETA]=(b>0.f)?b:0.f;
                 ((unsigned*)scalars)[SC_LPK2]=0u; }
    for (int e=tid; e<648; e+=256) sW[e]=fatoms[e];
    __syncthreads();
    if (tid<64){ int r=tid>>3, s=tid&7; float a=0.f;
        for (int k=0;k<81;++k) a=fmaf(sW[r*81+k],sW[s*81+k],a); sG[tid]=a; }
    __syncthreads();
    if (tid<64){
        int r8 = tid&7;
        float v = 1.f;
        for (int it=0; it<64; ++it){
            float nv=0.f;
            #pragma unroll
            for (int j=0;j<8;++j) nv = fmaf(sG[r8*8+j], __shfl(v,j,8), nv);
            float m = fabsf(nv);
            m = fmaxf(m, __shfl_xor(m,1,8));
            m = fmaxf(m, __shfl_xor(m,2,8));
            m = fmaxf(m, __shfl_xor(m,4,8));
            v = nv/m;
        }
        float wv=0.f;
        #pragma unroll
        for (int j=0;j<8;++j) wv = fmaf(sG[r8*8+j], __shfl(v,j,8), wv);
        float num=v*wv, den=v*v;
        num += __shfl_xor(num,1,8); num += __shfl_xor(num,2,8); num += __shfl_xor(num,4,8);
        den += __shfl_xor(den,1,8); den += __shfl_xor(den,2,8); den += __shfl_xor(den,4,8);
        if (tid==0) sSig = sqrtf(num/den);
    }
    __syncthreads();
    float inv_s = 1.f/sSig;
    for (int e=tid; e<648; e+=256) sW[e]*=inv_s;
    if (tid<64){ sG[tid]*=inv_s*inv_s; sP[tid]=((tid>>3)==(tid&7))?1.f:0.f; }
    __syncthreads();
    for (int it=0; it<15; ++it){
        if (tid<64) sF[tid] = (((tid>>3)==(tid&7))?1.5f:0.f) - 0.5f*sG[tid];
        __syncthreads();
        if (tid<64){ int r=tid>>3, c=tid&7; float ap=0.f, ag=0.f;
            #pragma unroll
            for (int k=0;k<8;++k){ float f=sF[r*8+k]; ap=fmaf(f,sP[k*8+c],ap); ag=fmaf(f,sG[k*8+c],ag); }
            sTmp[tid]=ap; sT[tid]=ag; }
        __syncthreads();
        if (tid<64){ int r=tid>>3, c=tid&7; float g2=0.f;
            #pragma unroll
            for (int k=0;k<8;++k) g2=fmaf(sT[r*8+k],sF[k*8+c],g2);
            sG[tid]=g2; sP[tid]=sTmp[tid]; }
        __syncthreads();
    }
    for (int e=tid; e<648; e+=256){ int r=e/81, j=e%81; float a=0.f;
        #pragma unroll
        for (int k=0;k<8;++k) a=fmaf(sP[r*8+k], sW[k*81+j], a);
        sWf[e]=a; }
    __syncthreads();
    for (int e=tid; e<6561; e+=256){ int i=e/81, j=e%81; float a=0.f;
        #pragma unroll
        for (int r=0;r<8;++r) a=fmaf(sWf[r*81+i],sWf[r*81+j],a);
        sGr[e]=a; gram_g[e]=a; }
    __syncthreads();
    if (tid<81){ float s=0.f; for (int k=0;k<81;++k) s+=sGr[tid*81+k]; rs[tid]=(1.f-s)/81.f; }
    __syncthreads();
    for (int e=tid; e<6561; e+=256){ int i=e/81, j=e%81;
        pf_g[e] = ((i==j)?1.f:0.f) - sGr[e] - rs[j]; }
}

// PP = pf^T pf (81x81), pf staged in LDS. 26 blocks x 256 thr.
__global__ __launch_bounds__(256) void k_PP(const float* __restrict__ pf, float* __restrict__ PP)
{
    __shared__ float spf[6561];
    for (int e=threadIdx.x; e<6561; e+=256) spf[e]=pf[e];
    __syncthreads();
    int e = blockIdx.x*256 + threadIdx.x;
    if (e>=6561) return;
    int al=e/81, be=e%81; float a=0.f;
    for (int c=0;c<81;++c) a=fmaf(spf[c*81+al], spf[c*81+be], a);
    PP[e]=a;
}

// proj_impulse (17x17) via PP lookups. One block, 320 thr (guard: t<289).
__global__ void k_impulse(const float* __restrict__ PP, float* __restrict__ pi)
{
    int t = threadIdx.x;
    if (t>=289) return;
    int h=t/17, w=t%17;
    float acc=0.f;
    for (int p=0;p<9;++p){
        int i2=(h+p-4+17)%17;
        if (i2<4||i2>12) continue;
        for (int q=0;q<9;++q){
            int j2=(w+q-4+17)%17;
            if (j2<4||j2>12) continue;
            int al=(12-i2)*9+(12-j2);
            int be=(8-p)*9+(8-q);
            acc += PP[al*81+be];
        }
    }
    pi[t]=acc;
}

// |FFT2(pi zero-padded to 128x128)|^2 max. 256 blocks x 64 thr (1 wave).
__global__ __launch_bounds__(64) void k_dft(const float* __restrict__ pi, float* __restrict__ scalars)
{
    __shared__ float spi[289], ct[128], st[128];
    int tid=threadIdx.x; int gid=blockIdx.x*64+tid;
    for (int e=tid; e<289; e+=64) spi[e]=pi[e];
    for (int e=tid; e<128; e+=64){ float ang=(float)e*(6.28318530717958647692f/128.f);
                  ct[e]=cosf(ang); st[e]=sinf(ang); }
    __syncthreads();
    int u=gid>>7, v=gid&127;
    float re=0.f, im=0.f;
    for (int i=0;i<17;++i){
        int ku=(u*i)&127;
        const float* prow=spi+i*17;
        for (int j=0;j<17;++j){
            int k=(ku+v*j)&127;
            float x=prow[j];
            re=fmaf(x,ct[k],re); im=fmaf(x,st[k],im);
        }
    }
    float m2=re*re+im*im;
    #pragma unroll
    for (int d=32; d; d>>=1) m2=fmaxf(m2, __shfl_down(m2,d));
    if (tid==0) atomicMax(((unsigned*)scalars)+SC_LPK2, __float_as_uint(m2));
}

// per-atom: center, subtract af@gram, row-normalize. Writes af_rn AND af_rnT.
__global__ __launch_bounds__(128) void k_atoms1(const float* __restrict__ atoms_in,
    const float* __restrict__ gram, float* __restrict__ af_rn, float* __restrict__ af_rnT)
{
    int a=blockIdx.x, tid=threadIdx.x;
    __shared__ float a0[81], a1[81], rbuf[128];
    float v = (tid<81)? atoms_in[a*81+tid] : 0.f;
    rbuf[tid]=v; __syncthreads();
    for (int off=64; off; off>>=1){ if (tid<off) rbuf[tid]+=rbuf[tid+off]; __syncthreads(); }
    float mean = rbuf[0]/81.f;
    __syncthreads();
    if (tid<81) a0[tid]=v-mean;
    __syncthreads();
    float w=0.f;
    if (tid<81){ float dot=0.f;
        for (int k=0;k<81;++k) dot=fmaf(a0[k], gram[k*81+tid], dot);
        w=a0[tid]-dot; a1[tid]=w; }
    rbuf[tid]=(tid<81)? w*w : 0.f;
    __syncthreads();
    for (int off=64; off; off>>=1){ if (tid<off) rbuf[tid]+=rbuf[tid+off]; __syncthreads(); }
    float inv = 1.f/sqrtf(rbuf[0]);
    if (tid<81){ float r=a1[tid]*inv; af_rn[a*81+tid]=r; af_rnT[tid*64+a]=r; }
}

// M = af_rn af_rn^T. 16 blocks x 256.
__global__ __launch_bounds__(256) void k_M(const float* __restrict__ af_rn,
    const float* __restrict__ af_rnT, float* __restrict__ M)
{
    int e=blockIdx.x*256+threadIdx.x;
    int i=e>>6, j=e&63;
    float a=0.f;
    for (int k=0;k<81;++k) a=fmaf(af_rn[i*81+k], af_rnT[(k<<6)+j], a);
    M[e]=a;
}

// OUT = IN*IN (symmetric). 16 blocks x 256. Chained for M^2..M^16.
__global__ __launch_bounds__(256) void k_M2(const float* __restrict__ IN,
    float* __restrict__ OUT)
{
    int e=blockIdx.x*256+threadIdx.x;
    int i=e>>6, j=e&63;
    float a=0.f;
    for (int k=0;k<64;++k) a=fmaf(IN[(i<<6)+k], IN[(k<<6)+j], a);
    OUT[e]=a;
}

// k_fin: one block. Power 8 iters on M^16, Rayleigh with M, finalize.
// Also writes atomsP: padded per-channel coefs [ch][p][12] (16B-aligned rows)
// for kB1's float4 coef loads.
__global__ __launch_bounds__(256) void k_fin(const float* __restrict__ Mg,
    const float* __restrict__ MPg, const float* __restrict__ af_rn,
    float* __restrict__ scalars,
    float* __restrict__ atoms_f, float* __restrict__ atomsT,
    float* __restrict__ atomsP, float* __restrict__ Xmat)
{
    __shared__ float sM[4096];
    __shared__ float sGc[2];
    int tid=threadIdx.x;
    for (int e=tid; e<4096; e+=256) sM[e]=Mg[e];
    for (int e=tid; e<64*112; e+=256) atomsP[e]=0.f;   // pads zeroed
    __syncthreads();
    if (tid<64){
        float m[64];
        const float4* mp = reinterpret_cast<const float4*>(MPg + (tid<<6));
        #pragma unroll
        for (int j4=0;j4<16;++j4){
            float4 v4=mp[j4];
            m[j4*4+0]=v4.x; m[j4*4+1]=v4.y; m[j4*4+2]=v4.z; m[j4*4+3]=v4.w;
        }
        float v = 1.0f + 0.01f*(float)tid;
        for (int it=0; it<8; ++it){
            float a0=0.f,a1=0.f,a2=0.f,a3=0.f;
            #pragma unroll
            for (int j=0;j<64;j+=4){
                a0=fmaf(m[j+0], __shfl(v,j+0), a0);
                a1=fmaf(m[j+1], __shfl(v,j+1), a1);
                a2=fmaf(m[j+2], __shfl(v,j+2), a2);
                a3=fmaf(m[j+3], __shfl(v,j+3), a3);
            }
            float nv=(a0+a1)+(a2+a3);
            float mx=fabsf(nv);
            #pragma unroll
            for (int d=1; d<64; d<<=1) mx=fmaxf(mx, __shfl_xor(mx,d));
            v=nv/mx;
        }
        float w0=0.f,w1=0.f,w2=0.f,w3=0.f;
        #pragma unroll
        for (int j=0;j<64;j+=4){
            w0=fmaf(sM[(tid<<6)+j+0], __shfl(v,j+0), w0);
            w1=fmaf(sM[(tid<<6)+j+1], __shfl(v,j+1), w1);
            w2=fmaf(sM[(tid<<6)+j+2], __shfl(v,j+2), w2);
            w3=fmaf(sM[(tid<<6)+j+3], __shfl(v,j+3), w3);
        }
        float wv=(w0+w1)+(w2+w3);
        float num=v*wv, den=v*v;
        #pragma unroll
        for (int d=1; d<64; d<<=1){ num+=__shfl_xor(num,d); den+=__shfl_xor(den,d); }
        if (tid==0){
            float sig = sqrtf(num/den);
            float b = scalars[SC_BETA];
            float s = sqrtf(0.99f/fmaxf(b,0.1f));
            float g = s/sig;
            scalars[SC_G]=g; scalars[SC_G2]=g*g;
            float lpk = sqrtf(__uint_as_float(((unsigned*)scalars)[SC_LPK2]));
            scalars[SC_L] = 1.01f*b*lpk;
            sGc[0]=g; sGc[1]=g*g;
        }
    }
    __syncthreads();
    float g=sGc[0], g2=sGc[1];
    for (int idx=tid; idx<5184; idx+=256){
        int a=idx/81, pq=idx-a*81;
        float v=g*af_rn[idx];
        atoms_f[idx]=v;
        atomsT[pq*64+a]=v;
        atomsP[a*112 + (pq/9)*12 + (pq%9)] = v;
    }
    for (int e=tid; e<4096; e+=256) Xmat[e]=g2*sM[e];
}

// ---------------------------------------------------------------------------
// kA: coefficient update, [b][ch][pix]. 1-row strips: grid (128,4), 512 thr
// (4 waves/SIMD). Thread owns [8ch x 2px]; stages own c/nc into regs + LDS.
// c-buffer rotation: nc_in becomes next iter's c; !act writes fix-up.
template<bool FIRST>
__global__ __launch_bounds__(512,4) void kA(const float* __restrict__ c_in,
    float* __restrict__ nc_in, const float* __restrict__ nimg,
    const float* __restrict__ Xmat, const float* __restrict__ atomsT,
    const float* __restrict__ scalars, const float* __restrict__ lmbda_p,
    const float* __restrict__ red_in,
    float* __restrict__ nc_out, float mom)
{
    int b=blockIdx.y, h0=blockIdx.x;       // one image row per block
    int tid=threadIdx.x;
    int wv = __builtin_amdgcn_readfirstlane(tid>>6);   // wave id 0..7
    int lane = tid&63;
    int co = wv*8;
    int px = lane*2;                        // 0..126, even
    __shared__ float sTemp[64*128];         // 32 KB
    __shared__ float simg[9*128];
    __shared__ float sAct;
    if (FIRST){ if (tid==0) sAct=1.f; }
    else if (tid<64){
        float sd=red_in[(b<<7)+(tid<<1)], si=red_in[(b<<7)+(tid<<1)+1];
        #pragma unroll
        for (int off=32; off; off>>=1){ sd+=__shfl_down(sd,off); si+=__shfl_down(si,off); }
        if (tid==0) sAct = (sd > TOLV*TOLV*si) ? 1.f : 0.f;
    }
    for (int e=tid; e<1152; e+=512)
        simg[e]=nimg[b*NPIX + (((h0-4+(e>>7))&127)<<7) + (e&127)];
    size_t sbase = (size_t)b*NPB + (h0<<7);
    float2 nv8[8], cv8[8];
    if (!FIRST){
        #pragma unroll
        for (int oc=0;oc<8;++oc){
            size_t a = sbase + (size_t)(co+oc)*NPIX + px;
            cv8[oc]=*reinterpret_cast<const float2*>(c_in + a);
            nv8[oc]=*reinterpret_cast<const float2*>(nc_in + a);
            float2 t;
            t.x=fmaf(mom,nv8[oc].x-cv8[oc].x,nv8[oc].x);
            t.y=fmaf(mom,nv8[oc].y-cv8[oc].y,nv8[oc].y);
            *reinterpret_cast<float2*>(sTemp + (co+oc)*128 + px) = t;
        }
    }
    __syncthreads();
    const float* Xo = Xmat + co;
    const float* Ao = atomsT + co;
    float acc[16];                          // [oc][2px]
    #pragma unroll
    for (int i=0;i<16;++i) acc[i]=0.f;
    if (!FIRST){
        for (int c=0;c<64;++c){
            float2 t=*reinterpret_cast<const float2*>(sTemp + c*128 + px);
            const float* Xr = Xo + (c<<6);
            #pragma unroll
            for (int oc=0;oc<8;++oc){
                float x=Xr[oc];
                acc[oc*2+0]=fmaf(x,t.x,acc[oc*2+0]);
                acc[oc*2+1]=fmaf(x,t.y,acc[oc*2+1]);
            }
        }
    }
    for (int p=0;p<9;++p){
        const float* srow = simg + p*128;
        float in10[10];
        #pragma unroll
        for (int j=0;j<10;++j) in10[j]=srow[(px-4+j)&127];
        #pragma unroll 3
        for (int q=0;q<9;++q){
            const float* Ar = Ao + ((p*9+q)<<6);
            #pragma unroll
            for (int oc=0;oc<8;++oc){
                float a=Ar[oc];
                acc[oc*2+0]=fmaf(a,-in10[q+0],acc[oc*2+0]);
                acc[oc*2+1]=fmaf(a,-in10[q+1],acc[oc*2+1]);
            }
        }
    }
    float beta=scalars[SC_BETA], lmb=lmbda_p[0];
    bool act = (sAct!=0.f);
    #pragma unroll
    for (int oc=0;oc<8;++oc){
        size_t a = sbase + (size_t)(co+oc)*NPIX + px;
        float2 nv, cv;
        if (FIRST){ nv=make_float2(0.f,0.f); cv=nv; }
        else { nv=nv8[oc]; cv=cv8[oc]; }
        float2 nw;
        {
            float t=FIRST?0.f:fmaf(mom,nv.x-cv.x,nv.x);
            float u=fmaf(-beta,acc[oc*2+0],t); float au=fabsf(u)-lmb;
            u=(au>0.f)?copysignf(au,u):0.f; nw.x=act?u:nv.x;
        }{
            float t=FIRST?0.f:fmaf(mom,nv.y-cv.y,nv.y);
            float u=fmaf(-beta,acc[oc*2+1],t); float au=fabsf(u)-lmb;
            u=(au>0.f)?copysignf(au,u):0.f; nw.y=act?u:nv.y;
        }
        *reinterpret_cast<float2*>(nc_out + a) = nw;
        if (FIRST){
            *reinterpret_cast<float2*>(nc_in + a) = make_float2(0.f,0.f);
        } else if (!act){
            *reinterpret_cast<float2*>(nc_in + a) = cv;
        }
    }
}

// kB1: dict_pred partials, rolling-row. grid (32 rowblk, 4 cgp, 4 b) =
// 512 blocks x 256 thr. Thread = 1 ch x 4 out-rows x 8 px: 12-row input
// window, each row loaded once (4 float4 = in16). p = or + 8 - ir (verified
// vs old r=row+4-p). Coefs: 3 aligned float4 from atomsP[ch][p][12].
// 16-ch butterfly shfl_xor reduce; lane chl==0 writes the partial.
__global__ __launch_bounds__(256) void kB1(const float* __restrict__ nc2,
    const float* __restrict__ atomsP, float* __restrict__ part)
{
    int b=blockIdx.z, cgp=blockIdx.y, rb=blockIdx.x;
    int t=threadIdx.x;
    int chl = t & 15;
    int cs  = t >> 4;                 // colslot 0..15
    int ch  = cgp*16 + chl;
    int r0  = rb*4;
    int cb  = cs*8;
    const float* chan = nc2 + (b*NCH + ch)*NPIX;
    const float* arowP = atomsP + ch*112;
    float acc[4][8];
    #pragma unroll
    for (int i=0;i<4;++i){
        #pragma unroll
        for (int j=0;j<8;++j) acc[i][j]=0.f;
    }
    for (int ir=0; ir<12; ++ir){
        int riabs = (r0 - 4 + ir) & 127;
        const float* rp_ = chan + (riabs<<7);
        float in16[16];
        #pragma unroll
        for (int k4=0;k4<4;++k4){
            int col=(cb-4+(k4<<2))&127;
            const float4 vv = *reinterpret_cast<const float4*>(rp_+col);
            in16[(k4<<2)+0]=vv.x; in16[(k4<<2)+1]=vv.y;
            in16[(k4<<2)+2]=vv.z; in16[(k4<<2)+3]=vv.w;
        }
        #pragma unroll
        for (int orr=0; orr<4; ++orr){
            int p = orr + 8 - ir;
            if (p>=0 && p<=8){                       // block-uniform branch
                const float4* cp4 = reinterpret_cast<const float4*>(arowP + p*12);
                float4 ca=cp4[0], cb4=cp4[1], cc=cp4[2];
                float c9[9];
                c9[0]=ca.x; c9[1]=ca.y; c9[2]=ca.z; c9[3]=ca.w;
                c9[4]=cb4.x; c9[5]=cb4.y; c9[6]=cb4.z; c9[7]=cb4.w;
                c9[8]=cc.x;
                #pragma unroll
                for (int q=0;q<9;++q){
                    float a=c9[q];
                    #pragma unroll
                    for (int k=0;k<8;++k)
                        acc[orr][k]=fmaf(in16[k+8-q], a, acc[orr][k]);
                }
            }
        }
    }
    // reduce over the 16 channels of this lane group (butterfly)
    #pragma unroll
    for (int i=0;i<4;++i){
        #pragma unroll
        for (int j=0;j<8;++j){
            float v=acc[i][j];
            v += __shfl_xor(v, 1, 16);
            v += __shfl_xor(v, 2, 16);
            v += __shfl_xor(v, 4, 16);
            v += __shfl_xor(v, 8, 16);
            acc[i][j]=v;
        }
    }
    if (chl==0){
        float* dst = part + (cgp*NB+b)*NPIX + (r0<<7) + cb;
        #pragma unroll
        for (int i=0;i<4;++i){
            #pragma unroll
            for (int j=0;j<8;++j) dst[(i<<7)+j]=acc[i][j];
        }
    }
}

// kB2: image update + residual partials. 512 thr: halves split the 17-tap
// p-loop (9/8), merged via LDS; px work+writes by half 0. Sums 4 partials.
template<bool FIRST>
__global__ __launch_bounds__(512) void kB2(const float* __restrict__ img,
    const float* __restrict__ nimg, const float* __restrict__ y,
    const float* __restrict__ part, const float* __restrict__ pi,
    const float* __restrict__ scalars, const float* __restrict__ red_in,
    float* __restrict__ img_out, float* __restrict__ nimg_out,
    float* __restrict__ red_out, float mom)
{
    int b=blockIdx.y, rp=blockIdx.x;
    int tid=threadIdx.x;
    int half=tid>>8, lid=tid&255;
    int ty=lid>>7, w=lid&127;
    int h0=rp*2;
    __shared__ float sti[18*128];
    __shared__ float spi[289];
    __shared__ float sP2[256];
    __shared__ float rsd[4], rsi[4];
    __shared__ float sAct;
    if (FIRST){ if (tid==0) sAct=1.f; }
    else if (tid<64){
        float sd=red_in[(b<<7)+(tid<<1)], si=red_in[(b<<7)+(tid<<1)+1];
        #pragma unroll
        for (int off=32; off; off>>=1){ sd+=__shfl_down(sd,off); si+=__shfl_down(si,off); }
        if (tid==0) sAct = (sd > TOLV*TOLV*si) ? 1.f : 0.f;
    }
    const float* ib  = img  + b*NPIX;
    const float* nib = nimg + b*NPIX;
    for (int e=tid; e<2304; e+=512){
        int r=e>>7, cc=e&127;
        int idx=(((h0-8+r)&127)<<7)+cc;
        float nv=nib[idx], v=ib[idx];
        sti[e]=fmaf(mom, nv-v, nv);
    }
    for (int e=tid; e<289; e+=512) spi[e]=pi[e];
    __syncthreads();
    float sp=0.f;
    int pn = 9 - half;
    for (int pk=0; pk<pn; ++pk){
        int p = half*9 + pk;
        const float* srow = sti + (ty+p)*128;
        const float* pr = spi + p*17;
        #pragma unroll
        for (int q=0;q<17;++q) sp=fmaf(srow[(w+q-8)&127], pr[q], sp);
    }
    if (half==1) sP2[lid]=sp;
    __syncthreads();
    if (tid<256){
        sp += sP2[lid];
        int pix=((h0+ty)<<7)+w;
        float dp=0.f;
        #pragma unroll
        for (int g=0; g<NPG; ++g) dp += part[(g*NB+b)*NPIX + pix];
        float ti = sti[(ty+8)*128 + w];
        float beta=scalars[SC_BETA], L=scalars[SC_L];
        float yv=y[b*NPIX+pix];
        float upd = ti - (ti - yv + beta*(sp - dp))/L;
        bool act = (sAct!=0.f);
        float iv=ib[pix], niv=nib[pix];
        float i2 = act? niv : iv;
        float ni2 = act? upd : niv;
        img_out[b*NPIX+pix]=i2;
        nimg_out[b*NPIX+pix]=ni2;
        float d=i2-ni2;
        float sd=d*d, si=i2*i2;
        #pragma unroll
        for (int off=32; off; off>>=1){ sd+=__shfl_down(sd,off); si+=__shfl_down(si,off); }
        if ((tid&63)==0){ rsd[tid>>6]=sd; rsi[tid>>6]=si; }
    }
    __syncthreads();
    if (tid==0){
        float a=rsd[0]+rsd[1]+rsd[2]+rsd[3];
        float c2=rsi[0]+rsi[1]+rsi[2]+rsi[3];
        red_out[(b<<7)+(rp<<1)+0]=a;
        red_out[(b<<7)+(rp<<1)+1]=c2;
    }
}

// ---------------------------------------------------------------------------
extern "C" void kernel_launch(void* const* d_in, const int* in_sizes, int n_in,
                              void* d_out, int out_size, void* d_ws, size_t ws_size,
                              hipStream_t stream)
{
    const float* y        = (const float*)d_in[0];
    const float* atoms_p  = (const float*)d_in[1];
    const float* fatoms_p = (const float*)d_in[2];
    const float* beta_p   = (const float*)d_in[3];
    const float* lmbda_p  = (const float*)d_in[4];
    float* out = (float*)d_out;
    float* w = (float*)d_ws;

    size_t off=0;
    float* cf[3];  cf[0]=w+off; off+=NCOEF; cf[1]=w+off; off+=NCOEF; cf[2]=w+off; off+=NCOEF;
    float* ib[2];  ib[0]=w+off;  off+=NIMG;  ib[1]=w+off;  off+=NIMG;
    float* nib[2]; nib[0]=w+off; off+=NIMG;  nib[1]=w+off; off+=NIMG;
    float* part=w+off;    off+=NPG*NIMG;
    float* red[2]; red[0]=w+off; off+=512; red[1]=w+off; off+=512;
    float* gram=w+off;    off+=6561;
    float* pf=w+off;      off+=6561;
    float* PP=w+off;      off+=6561;
    float* pi=w+off;      off+=512;
    float* af_rn=w+off;   off+=5184;
    float* af_rnT=w+off;  off+=5184;
    float* Mmat=w+off;    off+=4096;
    float* MA=w+off;      off+=4096;
    float* MB=w+off;      off+=4096;
    float* atoms_f=w+off; off+=5184;
    float* atomsT=w+off;  off+=5184;
    float* atomsP=w+off;  off+=64*112;
    float* Xmat=w+off;    off+=4096;
    float* scalars=w+off; off+=32;

    k_prep1<<<dim3(1),dim3(256),0,stream>>>(fatoms_p, beta_p, gram, pf, scalars);
    k_PP<<<dim3(26),dim3(256),0,stream>>>(pf, PP);
    k_impulse<<<dim3(1),dim3(320),0,stream>>>(PP, pi);
    k_dft<<<dim3(256),dim3(64),0,stream>>>(pi, scalars);
    k_atoms1<<<dim3(64),dim3(128),0,stream>>>(atoms_p, gram, af_rn, af_rnT);
    k_M<<<dim3(16),dim3(256),0,stream>>>(af_rn, af_rnT, Mmat);
    k_M2<<<dim3(16),dim3(256),0,stream>>>(Mmat, MA);   // M^2
    k_M2<<<dim3(16),dim3(256),0,stream>>>(MA, MB);     // M^4
    k_M2<<<dim3(16),dim3(256),0,stream>>>(MB, MA);     // M^8
    k_M2<<<dim3(16),dim3(256),0,stream>>>(MA, MB);     // M^16
    k_fin<<<dim3(1),dim3(256),0,stream>>>(Mmat, MB, af_rn, scalars, atoms_f, atomsT, atomsP, Xmat);

    // 3-buffer rotation: iter k uses (C=cf[ic], N=cf[in]); nc_out -> cf[io].
    int ic=0, in=1, io=2;
    int p=0;
    for (int k=1; k<=20; ++k){
        float mom = (float)(k-1)/(float)(k+2);
        const float* rin = red[(k-1)&1];
        float* rout = red[k&1];
        const float* img_i  = (k==1)? y : ib[p];
        const float* nimg_i = (k==1)? y : nib[p];
        float* nc_t  = (k==20)? (out+NIMG) : cf[io];
        float* nimg_t= (k==20)? out : nib[p^1];
        if (k==1){
            kA<true><<<dim3(128,4),dim3(512),0,stream>>>(cf[ic],cf[in],nimg_i,Xmat,atomsT,
                scalars,lmbda_p,rin, nc_t,mom);
        } else {
            kA<false><<<dim3(128,4),dim3(512),0,stream>>>(cf[ic],cf[in],nimg_i,Xmat,atomsT,
                scalars,lmbda_p,rin, nc_t,mom);
        }
        kB1<<<dim3(32,4,4),dim3(256),0,stream>>>(nc_t, atomsP, part);
        if (k==1){
            kB2<true><<<dim3(64,4),dim3(512),0,stream>>>(img_i,nimg_i,y,part,pi,scalars,rin,
                ib[p^1],nimg_t,rout,mom);
        } else {
            kB2<false><<<dim3(64,4),dim3(512),0,stream>>>(img_i,nimg_i,y,part,pi,scalars,rin,
                ib[p^1],nimg_t,rout,mom);
        }
        int t=ic; ic=in; in=io; io=t;
        p^=1;
    }
}

// Round 22
// 1158.912 us; speedup vs baseline: 1.2675x; 1.2675x over previous
//
#include <hip/hip_runtime.h>
#include <math.h>

// ---------------------------------------------------------------------------
// Dictionary_56212531970303 : FISTA dictionary forward on MI355X, fp32.
// Layout: coefficient state [b][ch][pix]. Per-INSTRUCTION contiguity rule
// (round-13): state loads/stores = 64 lanes x (float4|float2) contiguous.
// Round-19: c-buffer pointer rotation (3-buffer cycle; !act writes fix-up).
// Round-21: kB1 REVERTED to 32-cgroup x 2ch form — rolling-row experiment
// (round-20) cut L2 traffic 3x but lost 4x to latency-exposed dependency
// chains (VALUBusy 13%, hbm 635 GB/s: neither pipe busy). Lesson: traffic
// cuts that serialize lose when the kernel wasn't BW-bound.
// Setup: prep1, k_PP, k_impulse, k_dft, atoms1, k_M, k_M2 x4, k_fin.
// NOTE: every "if (tid<N)" with N>blockDim must be a grid-stride loop —
// round-2/3 regression (absmax 0.134).
// ---------------------------------------------------------------------------

#define NB 4
#define NCH 64
#define NPIX 16384              // 128*128
#define NPB (NCH*NPIX)
#define NCOEF (NB*NCH*NPIX)     // 4194304
#define NIMG  (NB*NPIX)         // 65536
#define NPG 32                  // partial channel-groups (2 ch each)
#define TOLV 1e-4f

#define SC_BETA 0
#define SC_L    1
#define SC_G    4
#define SC_G2   5
#define SC_LPK2 6

// ---------------------------------------------------------------------------
// prep1: one block. bjorck via 8x8 gram-iteration; writes gram + pf + scalars.
__global__ __launch_bounds__(256) void k_prep1(const float* __restrict__ fatoms,
    const float* __restrict__ beta_p,
    float* __restrict__ gram_g, float* __restrict__ pf_g,
    float* __restrict__ scalars)
{
    __shared__ float sW[648], sWf[648];
    __shared__ float sG[64], sP[64], sF[64], sT[64], sTmp[64];
    __shared__ float sGr[6561];
    __shared__ float rs[81];
    __shared__ float sSig;
    int tid = threadIdx.x;
    if (tid==0){ float b=beta_p[0]; scalars[SC_BETA]=(b>0.f)?b:0.f;
                 ((unsigned*)scalars)[SC_LPK2]=0u; }
    for (int e=tid; e<648; e+=256) sW[e]=fatoms[e];
    __syncthreads();
    if (tid<64){ int r=tid>>3, s=tid&7; float a=0.f;
        for (int k=0;k<81;++k) a=fmaf(sW[r*81+k],sW[s*81+k],a); sG[tid]=a; }
    __syncthreads();
    if (tid<64){
        int r8 = tid&7;
        float v = 1.f;
        for (int it=0; it<64; ++it){
            float nv=0.f;
            #pragma unroll
            for (int j=0;j<8;++j) nv = fmaf(sG[r8*8+j], __shfl(v,j,8), nv);
            float m = fabsf(nv);
            m = fmaxf(m, __shfl_xor(m,1,8));
            m = fmaxf(m, __shfl_xor(m,2,8));
            m = fmaxf(m, __shfl_xor(m,4,8));
            v = nv/m;
        }
        float wv=0.f;
        #pragma unroll
        for (int j=0;j<8;++j) wv = fmaf(sG[r8*8+j], __shfl(v,j,8), wv);
        float num=v*wv, den=v*v;
        num += __shfl_xor(num,1,8); num += __shfl_xor(num,2,8); num += __shfl_xor(num,4,8);
        den += __shfl_xor(den,1,8); den += __shfl_xor(den,2,8); den += __shfl_xor(den,4,8);
        if (tid==0) sSig = sqrtf(num/den);
    }
    __syncthreads();
    float inv_s = 1.f/sSig;
    for (int e=tid; e<648; e+=256) sW[e]*=inv_s;
    if (tid<64){ sG[tid]*=inv_s*inv_s; sP[tid]=((tid>>3)==(tid&7))?1.f:0.f; }
    __syncthreads();
    for (int it=0; it<15; ++it){
        if (tid<64) sF[tid] = (((tid>>3)==(tid&7))?1.5f:0.f) - 0.5f*sG[tid];
        __syncthreads();
        if (tid<64){ int r=tid>>3, c=tid&7; float ap=0.f, ag=0.f;
            #pragma unroll
            for (int k=0;k<8;++k){ float f=sF[r*8+k]; ap=fmaf(f,sP[k*8+c],ap); ag=fmaf(f,sG[k*8+c],ag); }
            sTmp[tid]=ap; sT[tid]=ag; }
        __syncthreads();
        if (tid<64){ int r=tid>>3, c=tid&7; float g2=0.f;
            #pragma unroll
            for (int k=0;k<8;++k) g2=fmaf(sT[r*8+k],sF[k*8+c],g2);
            sG[tid]=g2; sP[tid]=sTmp[tid]; }
        __syncthreads();
    }
    for (int e=tid; e<648; e+=256){ int r=e/81, j=e%81; float a=0.f;
        #pragma unroll
        for (int k=0;k<8;++k) a=fmaf(sP[r*8+k], sW[k*81+j], a);
        sWf[e]=a; }
    __syncthreads();
    for (int e=tid; e<6561; e+=256){ int i=e/81, j=e%81; float a=0.f;
        #pragma unroll
        for (int r=0;r<8;++r) a=fmaf(sWf[r*81+i],sWf[r*81+j],a);
        sGr[e]=a; gram_g[e]=a; }
    __syncthreads();
    if (tid<81){ float s=0.f; for (int k=0;k<81;++k) s+=sGr[tid*81+k]; rs[tid]=(1.f-s)/81.f; }
    __syncthreads();
    for (int e=tid; e<6561; e+=256){ int i=e/81, j=e%81;
        pf_g[e] = ((i==j)?1.f:0.f) - sGr[e] - rs[j]; }
}

// PP = pf^T pf (81x81), pf staged in LDS. 26 blocks x 256 thr.
__global__ __launch_bounds__(256) void k_PP(const float* __restrict__ pf, float* __restrict__ PP)
{
    __shared__ float spf[6561];
    for (int e=threadIdx.x; e<6561; e+=256) spf[e]=pf[e];
    __syncthreads();
    int e = blockIdx.x*256 + threadIdx.x;
    if (e>=6561) return;
    int al=e/81, be=e%81; float a=0.f;
    for (int c=0;c<81;++c) a=fmaf(spf[c*81+al], spf[c*81+be], a);
    PP[e]=a;
}

// proj_impulse (17x17) via PP lookups. One block, 320 thr (guard: t<289).
__global__ void k_impulse(const float* __restrict__ PP, float* __restrict__ pi)
{
    int t = threadIdx.x;
    if (t>=289) return;
    int h=t/17, w=t%17;
    float acc=0.f;
    for (int p=0;p<9;++p){
        int i2=(h+p-4+17)%17;
        if (i2<4||i2>12) continue;
        for (int q=0;q<9;++q){
            int j2=(w+q-4+17)%17;
            if (j2<4||j2>12) continue;
            int al=(12-i2)*9+(12-j2);
            int be=(8-p)*9+(8-q);
            acc += PP[al*81+be];
        }
    }
    pi[t]=acc;
}

// |FFT2(pi zero-padded to 128x128)|^2 max. 256 blocks x 64 thr (1 wave).
__global__ __launch_bounds__(64) void k_dft(const float* __restrict__ pi, float* __restrict__ scalars)
{
    __shared__ float spi[289], ct[128], st[128];
    int tid=threadIdx.x; int gid=blockIdx.x*64+tid;
    for (int e=tid; e<289; e+=64) spi[e]=pi[e];
    for (int e=tid; e<128; e+=64){ float ang=(float)e*(6.28318530717958647692f/128.f);
                  ct[e]=cosf(ang); st[e]=sinf(ang); }
    __syncthreads();
    int u=gid>>7, v=gid&127;
    float re=0.f, im=0.f;
    for (int i=0;i<17;++i){
        int ku=(u*i)&127;
        const float* prow=spi+i*17;
        for (int j=0;j<17;++j){
            int k=(ku+v*j)&127;
            float x=prow[j];
            re=fmaf(x,ct[k],re); im=fmaf(x,st[k],im);
        }
    }
    float m2=re*re+im*im;
    #pragma unroll
    for (int d=32; d; d>>=1) m2=fmaxf(m2, __shfl_down(m2,d));
    if (tid==0) atomicMax(((unsigned*)scalars)+SC_LPK2, __float_as_uint(m2));
}

// per-atom: center, subtract af@gram, row-normalize. Writes af_rn AND af_rnT.
__global__ __launch_bounds__(128) void k_atoms1(const float* __restrict__ atoms_in,
    const float* __restrict__ gram, float* __restrict__ af_rn, float* __restrict__ af_rnT)
{
    int a=blockIdx.x, tid=threadIdx.x;
    __shared__ float a0[81], a1[81], rbuf[128];
    float v = (tid<81)? atoms_in[a*81+tid] : 0.f;
    rbuf[tid]=v; __syncthreads();
    for (int off=64; off; off>>=1){ if (tid<off) rbuf[tid]+=rbuf[tid+off]; __syncthreads(); }
    float mean = rbuf[0]/81.f;
    __syncthreads();
    if (tid<81) a0[tid]=v-mean;
    __syncthreads();
    float w=0.f;
    if (tid<81){ float dot=0.f;
        for (int k=0;k<81;++k) dot=fmaf(a0[k], gram[k*81+tid], dot);
        w=a0[tid]-dot; a1[tid]=w; }
    rbuf[tid]=(tid<81)? w*w : 0.f;
    __syncthreads();
    for (int off=64; off; off>>=1){ if (tid<off) rbuf[tid]+=rbuf[tid+off]; __syncthreads(); }
    float inv = 1.f/sqrtf(rbuf[0]);
    if (tid<81){ float r=a1[tid]*inv; af_rn[a*81+tid]=r; af_rnT[tid*64+a]=r; }
}

// M = af_rn af_rn^T. 16 blocks x 256.
__global__ __launch_bounds__(256) void k_M(const float* __restrict__ af_rn,
    const float* __restrict__ af_rnT, float* __restrict__ M)
{
    int e=blockIdx.x*256+threadIdx.x;
    int i=e>>6, j=e&63;
    float a=0.f;
    for (int k=0;k<81;++k) a=fmaf(af_rn[i*81+k], af_rnT[(k<<6)+j], a);
    M[e]=a;
}

// OUT = IN*IN (symmetric). 16 blocks x 256. Chained for M^2..M^16.
__global__ __launch_bounds__(256) void k_M2(const float* __restrict__ IN,
    float* __restrict__ OUT)
{
    int e=blockIdx.x*256+threadIdx.x;
    int i=e>>6, j=e&63;
    float a=0.f;
    for (int k=0;k<64;++k) a=fmaf(IN[(i<<6)+k], IN[(k<<6)+j], a);
    OUT[e]=a;
}

// k_fin: one block. Power 8 iters on M^16, Rayleigh with M, finalize.
__global__ __launch_bounds__(256) void k_fin(const float* __restrict__ Mg,
    const float* __restrict__ MPg, const float* __restrict__ af_rn,
    float* __restrict__ scalars,
    float* __restrict__ atoms_f, float* __restrict__ atomsT, float* __restrict__ Xmat)
{
    __shared__ float sM[4096];
    __shared__ float sGc[2];
    int tid=threadIdx.x;
    for (int e=tid; e<4096; e+=256) sM[e]=Mg[e];
    __syncthreads();
    if (tid<64){
        float m[64];
        const float4* mp = reinterpret_cast<const float4*>(MPg + (tid<<6));
        #pragma unroll
        for (int j4=0;j4<16;++j4){
            float4 v4=mp[j4];
            m[j4*4+0]=v4.x; m[j4*4+1]=v4.y; m[j4*4+2]=v4.z; m[j4*4+3]=v4.w;
        }
        float v = 1.0f + 0.01f*(float)tid;
        for (int it=0; it<8; ++it){
            float a0=0.f,a1=0.f,a2=0.f,a3=0.f;
            #pragma unroll
            for (int j=0;j<64;j+=4){
                a0=fmaf(m[j+0], __shfl(v,j+0), a0);
                a1=fmaf(m[j+1], __shfl(v,j+1), a1);
                a2=fmaf(m[j+2], __shfl(v,j+2), a2);
                a3=fmaf(m[j+3], __shfl(v,j+3), a3);
            }
            float nv=(a0+a1)+(a2+a3);
            float mx=fabsf(nv);
            #pragma unroll
            for (int d=1; d<64; d<<=1) mx=fmaxf(mx, __shfl_xor(mx,d));
            v=nv/mx;
        }
        float w0=0.f,w1=0.f,w2=0.f,w3=0.f;
        #pragma unroll
        for (int j=0;j<64;j+=4){
            w0=fmaf(sM[(tid<<6)+j+0], __shfl(v,j+0), w0);
            w1=fmaf(sM[(tid<<6)+j+1], __shfl(v,j+1), w1);
            w2=fmaf(sM[(tid<<6)+j+2], __shfl(v,j+2), w2);
            w3=fmaf(sM[(tid<<6)+j+3], __shfl(v,j+3), w3);
        }
        float wv=(w0+w1)+(w2+w3);
        float num=v*wv, den=v*v;
        #pragma unroll
        for (int d=1; d<64; d<<=1){ num+=__shfl_xor(num,d); den+=__shfl_xor(den,d); }
        if (tid==0){
            float sig = sqrtf(num/den);
            float b = scalars[SC_BETA];
            float s = sqrtf(0.99f/fmaxf(b,0.1f));
            float g = s/sig;
            scalars[SC_G]=g; scalars[SC_G2]=g*g;
            float lpk = sqrtf(__uint_as_float(((unsigned*)scalars)[SC_LPK2]));
            scalars[SC_L] = 1.01f*b*lpk;
            sGc[0]=g; sGc[1]=g*g;
        }
    }
    __syncthreads();
    float g=sGc[0], g2=sGc[1];
    for (int idx=tid; idx<5184; idx+=256){
        int a=idx/81, pq=idx-a*81;
        float v=g*af_rn[idx];
        atoms_f[idx]=v;
        atomsT[pq*64+a]=v;
    }
    for (int e=tid; e<4096; e+=256) Xmat[e]=g2*sM[e];
}

// ---------------------------------------------------------------------------
// kA: coefficient update, [b][ch][pix]. 1-row strips: grid (128,4), 512 thr
// (4 waves/SIMD). Thread owns [8ch x 2px]; stages own c/nc into regs + LDS.
// c-buffer rotation: nc_in becomes next iter's c; !act writes fix-up.
template<bool FIRST>
__global__ __launch_bounds__(512,4) void kA(const float* __restrict__ c_in,
    float* __restrict__ nc_in, const float* __restrict__ nimg,
    const float* __restrict__ Xmat, const float* __restrict__ atomsT,
    const float* __restrict__ scalars, const float* __restrict__ lmbda_p,
    const float* __restrict__ red_in,
    float* __restrict__ nc_out, float mom)
{
    int b=blockIdx.y, h0=blockIdx.x;       // one image row per block
    int tid=threadIdx.x;
    int wv = __builtin_amdgcn_readfirstlane(tid>>6);   // wave id 0..7
    int lane = tid&63;
    int co = wv*8;
    int px = lane*2;                        // 0..126, even
    __shared__ float sTemp[64*128];         // 32 KB
    __shared__ float simg[9*128];
    __shared__ float sAct;
    if (FIRST){ if (tid==0) sAct=1.f; }
    else if (tid<64){
        float sd=red_in[(b<<7)+(tid<<1)], si=red_in[(b<<7)+(tid<<1)+1];
        #pragma unroll
        for (int off=32; off; off>>=1){ sd+=__shfl_down(sd,off); si+=__shfl_down(si,off); }
        if (tid==0) sAct = (sd > TOLV*TOLV*si) ? 1.f : 0.f;
    }
    for (int e=tid; e<1152; e+=512)
        simg[e]=nimg[b*NPIX + (((h0-4+(e>>7))&127)<<7) + (e&127)];
    size_t sbase = (size_t)b*NPB + (h0<<7);
    float2 nv8[8], cv8[8];
    if (!FIRST){
        #pragma unroll
        for (int oc=0;oc<8;++oc){
            size_t a = sbase + (size_t)(co+oc)*NPIX + px;
            cv8[oc]=*reinterpret_cast<const float2*>(c_in + a);
            nv8[oc]=*reinterpret_cast<const float2*>(nc_in + a);
            float2 t;
            t.x=fmaf(mom,nv8[oc].x-cv8[oc].x,nv8[oc].x);
            t.y=fmaf(mom,nv8[oc].y-cv8[oc].y,nv8[oc].y);
            *reinterpret_cast<float2*>(sTemp + (co+oc)*128 + px) = t;
        }
    }
    __syncthreads();
    const float* Xo = Xmat + co;
    const float* Ao = atomsT + co;
    float acc[16];                          // [oc][2px]
    #pragma unroll
    for (int i=0;i<16;++i) acc[i]=0.f;
    if (!FIRST){
        for (int c=0;c<64;++c){
            float2 t=*reinterpret_cast<const float2*>(sTemp + c*128 + px);
            const float* Xr = Xo + (c<<6);
            #pragma unroll
            for (int oc=0;oc<8;++oc){
                float x=Xr[oc];
                acc[oc*2+0]=fmaf(x,t.x,acc[oc*2+0]);
                acc[oc*2+1]=fmaf(x,t.y,acc[oc*2+1]);
            }
        }
    }
    for (int p=0;p<9;++p){
        const float* srow = simg + p*128;
        float in10[10];
        #pragma unroll
        for (int j=0;j<10;++j) in10[j]=srow[(px-4+j)&127];
        #pragma unroll 3
        for (int q=0;q<9;++q){
            const float* Ar = Ao + ((p*9+q)<<6);
            #pragma unroll
            for (int oc=0;oc<8;++oc){
                float a=Ar[oc];
                acc[oc*2+0]=fmaf(a,-in10[q+0],acc[oc*2+0]);
                acc[oc*2+1]=fmaf(a,-in10[q+1],acc[oc*2+1]);
            }
        }
    }
    float beta=scalars[SC_BETA], lmb=lmbda_p[0];
    bool act = (sAct!=0.f);
    #pragma unroll
    for (int oc=0;oc<8;++oc){
        size_t a = sbase + (size_t)(co+oc)*NPIX + px;
        float2 nv, cv;
        if (FIRST){ nv=make_float2(0.f,0.f); cv=nv; }
        else { nv=nv8[oc]; cv=cv8[oc]; }
        float2 nw;
        {
            float t=FIRST?0.f:fmaf(mom,nv.x-cv.x,nv.x);
            float u=fmaf(-beta,acc[oc*2+0],t); float au=fabsf(u)-lmb;
            u=(au>0.f)?copysignf(au,u):0.f; nw.x=act?u:nv.x;
        }{
            float t=FIRST?0.f:fmaf(mom,nv.y-cv.y,nv.y);
            float u=fmaf(-beta,acc[oc*2+1],t); float au=fabsf(u)-lmb;
            u=(au>0.f)?copysignf(au,u):0.f; nw.y=act?u:nv.y;
        }
        *reinterpret_cast<float2*>(nc_out + a) = nw;
        if (FIRST){
            *reinterpret_cast<float2*>(nc_in + a) = make_float2(0.f,0.f);
        } else if (!act){
            *reinterpret_cast<float2*>(nc_in + a) = cv;
        }
    }
}

// kB1: dict_pred partials, CHANNEL-split (round-18 proven form). grid
// (8 rowblk, 32 cgroup, 4 b) = 1024 blocks of 256 thr (4 waves/SIMD).
// 16 rows/block, 8 px/thread, 2 ch per cgroup (18 fma per float4 load).
__global__ __launch_bounds__(256,4) void kB1(const float* __restrict__ nc2,
    const float* __restrict__ atoms_f, float* __restrict__ part)
{
    int b=blockIdx.z, cg=blockIdx.y, pb=blockIdx.x;
    int t=threadIdx.x;
    int row = pb*16 + (t>>4);
    int cb  = (t&15)*8;
    const float* src = nc2 + (b*NCH + cg*2)*NPIX;
    float acc[8];
    #pragma unroll
    for (int k=0;k<8;++k) acc[k]=0.f;
    for (int c=0;c<2;++c){
        const float* chan = src + c*NPIX;
        const float* arow = atoms_f + (cg*2+c)*81;
        #pragma unroll 3
        for (int p=0;p<9;++p){
            int r=(row+4-p)&127;
            const float* rp_ = chan + (r<<7);
            float in16[16];
            #pragma unroll
            for (int k4=0;k4<4;++k4){
                int col=(cb-4+(k4<<2))&127;
                const float4 vv = *reinterpret_cast<const float4*>(rp_+col);
                in16[(k4<<2)+0]=vv.x; in16[(k4<<2)+1]=vv.y;
                in16[(k4<<2)+2]=vv.z; in16[(k4<<2)+3]=vv.w;
            }
            #pragma unroll
            for (int q=0;q<9;++q){
                float a = arow[p*9+q];
                #pragma unroll
                for (int k=0;k<8;++k) acc[k]=fmaf(in16[k+8-q], a, acc[k]);
            }
        }
    }
    float* dst = part + (cg*NB+b)*NPIX + (row<<7) + cb;
    #pragma unroll
    for (int k=0;k<8;++k) dst[k]=acc[k];
}

// kB2: image update + residual partials. 512 thr: halves split the 17-tap
// p-loop (9/8), merged via LDS; px work+writes by half 0. Sums 32 partials.
template<bool FIRST>
__global__ __launch_bounds__(512) void kB2(const float* __restrict__ img,
    const float* __restrict__ nimg, const float* __restrict__ y,
    const float* __restrict__ part, const float* __restrict__ pi,
    const float* __restrict__ scalars, const float* __restrict__ red_in,
    float* __restrict__ img_out, float* __restrict__ nimg_out,
    float* __restrict__ red_out, float mom)
{
    int b=blockIdx.y, rp=blockIdx.x;
    int tid=threadIdx.x;
    int half=tid>>8, lid=tid&255;
    int ty=lid>>7, w=lid&127;
    int h0=rp*2;
    __shared__ float sti[18*128];
    __shared__ float spi[289];
    __shared__ float sP2[256];
    __shared__ float rsd[4], rsi[4];
    __shared__ float sAct;
    if (FIRST){ if (tid==0) sAct=1.f; }
    else if (tid<64){
        float sd=red_in[(b<<7)+(tid<<1)], si=red_in[(b<<7)+(tid<<1)+1];
        #pragma unroll
        for (int off=32; off; off>>=1){ sd+=__shfl_down(sd,off); si+=__shfl_down(si,off); }
        if (tid==0) sAct = (sd > TOLV*TOLV*si) ? 1.f : 0.f;
    }
    const float* ib  = img  + b*NPIX;
    const float* nib = nimg + b*NPIX;
    for (int e=tid; e<2304; e+=512){
        int r=e>>7, cc=e&127;
        int idx=(((h0-8+r)&127)<<7)+cc;
        float nv=nib[idx], v=ib[idx];
        sti[e]=fmaf(mom, nv-v, nv);
    }
    for (int e=tid; e<289; e+=512) spi[e]=pi[e];
    __syncthreads();
    float sp=0.f;
    int pn = 9 - half;
    for (int pk=0; pk<pn; ++pk){
        int p = half*9 + pk;
        const float* srow = sti + (ty+p)*128;
        const float* pr = spi + p*17;
        #pragma unroll
        for (int q=0;q<17;++q) sp=fmaf(srow[(w+q-8)&127], pr[q], sp);
    }
    if (half==1) sP2[lid]=sp;
    __syncthreads();
    if (tid<256){
        sp += sP2[lid];
        int pix=((h0+ty)<<7)+w;
        float dp=0.f;
        #pragma unroll
        for (int g=0; g<NPG; ++g) dp += part[(g*NB+b)*NPIX + pix];
        float ti = sti[(ty+8)*128 + w];
        float beta=scalars[SC_BETA], L=scalars[SC_L];
        float yv=y[b*NPIX+pix];
        float upd = ti - (ti - yv + beta*(sp - dp))/L;
        bool act = (sAct!=0.f);
        float iv=ib[pix], niv=nib[pix];
        float i2 = act? niv : iv;
        float ni2 = act? upd : niv;
        img_out[b*NPIX+pix]=i2;
        nimg_out[b*NPIX+pix]=ni2;
        float d=i2-ni2;
        float sd=d*d, si=i2*i2;
        #pragma unroll
        for (int off=32; off; off>>=1){ sd+=__shfl_down(sd,off); si+=__shfl_down(si,off); }
        if ((tid&63)==0){ rsd[tid>>6]=sd; rsi[tid>>6]=si; }
    }
    __syncthreads();
    if (tid==0){
        float a=rsd[0]+rsd[1]+rsd[2]+rsd[3];
        float c2=rsi[0]+rsi[1]+rsi[2]+rsi[3];
        red_out[(b<<7)+(rp<<1)+0]=a;
        red_out[(b<<7)+(rp<<1)+1]=c2;
    }
}

// ---------------------------------------------------------------------------
extern "C" void kernel_launch(void* const* d_in, const int* in_sizes, int n_in,
                              void* d_out, int out_size, void* d_ws, size_t ws_size,
                              hipStream_t stream)
{
    const float* y        = (const float*)d_in[0];
    const float* atoms_p  = (const float*)d_in[1];
    const float* fatoms_p = (const float*)d_in[2];
    const float* beta_p   = (const float*)d_in[3];
    const float* lmbda_p  = (const float*)d_in[4];
    float* out = (float*)d_out;
    float* w = (float*)d_ws;

    size_t off=0;
    float* cf[3];  cf[0]=w+off; off+=NCOEF; cf[1]=w+off; off+=NCOEF; cf[2]=w+off; off+=NCOEF;
    float* ib[2];  ib[0]=w+off;  off+=NIMG;  ib[1]=w+off;  off+=NIMG;
    float* nib[2]; nib[0]=w+off; off+=NIMG;  nib[1]=w+off; off+=NIMG;
    float* part=w+off;    off+=NPG*NIMG;
    float* red[2]; red[0]=w+off; off+=512; red[1]=w+off; off+=512;
    float* gram=w+off;    off+=6561;
    float* pf=w+off;      off+=6561;
    float* PP=w+off;      off+=6561;
    float* pi=w+off;      off+=512;
    float* af_rn=w+off;   off+=5184;
    float* af_rnT=w+off;  off+=5184;
    float* Mmat=w+off;    off+=4096;
    float* MA=w+off;      off+=4096;
    float* MB=w+off;      off+=4096;
    float* atoms_f=w+off; off+=5184;
    float* atomsT=w+off;  off+=5184;
    float* Xmat=w+off;    off+=4096;
    float* scalars=w+off; off+=32;

    k_prep1<<<dim3(1),dim3(256),0,stream>>>(fatoms_p, beta_p, gram, pf, scalars);
    k_PP<<<dim3(26),dim3(256),0,stream>>>(pf, PP);
    k_impulse<<<dim3(1),dim3(320),0,stream>>>(PP, pi);
    k_dft<<<dim3(256),dim3(64),0,stream>>>(pi, scalars);
    k_atoms1<<<dim3(64),dim3(128),0,stream>>>(atoms_p, gram, af_rn, af_rnT);
    k_M<<<dim3(16),dim3(256),0,stream>>>(af_rn, af_rnT, Mmat);
    k_M2<<<dim3(16),dim3(256),0,stream>>>(Mmat, MA);   // M^2
    k_M2<<<dim3(16),dim3(256),0,stream>>>(MA, MB);     // M^4
    k_M2<<<dim3(16),dim3(256),0,stream>>>(MB, MA);     // M^8
    k_M2<<<dim3(16),dim3(256),0,stream>>>(MA, MB);     // M^16
    k_fin<<<dim3(1),dim3(256),0,stream>>>(Mmat, MB, af_rn, scalars, atoms_f, atomsT, Xmat);

    // 3-buffer rotation: iter k uses (C=cf[ic], N=cf[in]); nc_out -> cf[io].
    int ic=0, in=1, io=2;
    int p=0;
    for (int k=1; k<=20; ++k){
        float mom = (float)(k-1)/(float)(k+2);
        const float* rin = red[(k-1)&1];
        float* rout = red[k&1];
        const float* img_i  = (k==1)? y : ib[p];
        const float* nimg_i = (k==1)? y : nib[p];
        float* nc_t  = (k==20)? (out+NIMG) : cf[io];
        float* nimg_t= (k==20)? out : nib[p^1];
        if (k==1){
            kA<true><<<dim3(128,4),dim3(512),0,stream>>>(cf[ic],cf[in],nimg_i,Xmat,atomsT,
                scalars,lmbda_p,rin, nc_t,mom);
        } else {
            kA<false><<<dim3(128,4),dim3(512),0,stream>>>(cf[ic],cf[in],nimg_i,Xmat,atomsT,
                scalars,lmbda_p,rin, nc_t,mom);
        }
        kB1<<<dim3(8,32,4),dim3(256),0,stream>>>(nc_t, atoms_f, part);
        if (k==1){
            kB2<true><<<dim3(64,4),dim3(512),0,stream>>>(img_i,nimg_i,y,part,pi,scalars,rin,
                ib[p^1],nimg_t,rout,mom);
        } else {
            kB2<false><<<dim3(64,4),dim3(512),0,stream>>>(img_i,nimg_i,y,part,pi,scalars,rin,
                ib[p^1],nimg_t,rout,mom);
        }
        int t=ic; ic=in; in=io; io=t;
        p^=1;
    }
}